// Round 2
// baseline (93.812 us; speedup 1.0000x reference)
//
#include <hip/hip_runtime.h>
#include <math.h>

// 4-qubit statevector simulator, circuit fully hardcoded from DESIGN.
// Qubit q corresponds to bit (3-q) of the state index (q=0 is MSB).

#define DEVI static __device__ __forceinline__

// ---- gate helpers: all loops constant-bound, fully unrolled -> registers ----

template<int Q> DEVI void gH(float* vr, float* vi) {
  constexpr int m = 1 << (3 - Q);
  const float K = 0.70710678118654752440f;
#pragma unroll
  for (int i = 0; i < 16; ++i) if (!(i & m)) {
    const int j = i | m;
    float ar = vr[i], ai = vi[i], br = vr[j], bi = vi[j];
    vr[i] = (ar + br) * K; vi[i] = (ai + bi) * K;
    vr[j] = (ar - br) * K; vi[j] = (ai - bi) * K;
  }
}

template<int Q> DEVI void gX(float* vr, float* vi) {
  constexpr int m = 1 << (3 - Q);
#pragma unroll
  for (int i = 0; i < 16; ++i) if (!(i & m)) {
    const int j = i | m; float t;
    t = vr[i]; vr[i] = vr[j]; vr[j] = t;
    t = vi[i]; vi[i] = vi[j]; vi[j] = t;
  }
}

template<int Q> DEVI void gY(float* vr, float* vi) {
  constexpr int m = 1 << (3 - Q);
#pragma unroll
  for (int i = 0; i < 16; ++i) if (!(i & m)) {
    const int j = i | m;
    float ar = vr[i], ai = vi[i], br = vr[j], bi = vi[j];
    // out0 = -i*b ; out1 = i*a
    vr[i] = bi;  vi[i] = -br;
    vr[j] = -ai; vi[j] = ar;
  }
}

template<int Q> DEVI void gZ(float* vr, float* vi) {
  constexpr int m = 1 << (3 - Q);
#pragma unroll
  for (int i = 0; i < 16; ++i) if (i & m) { vr[i] = -vr[i]; vi[i] = -vi[i]; }
}

// RY(theta): [[c,-s],[s,c]], c=cos(theta/2), s=sin(theta/2)
template<int Q> DEVI void gRY(float* vr, float* vi, float c, float s) {
  constexpr int m = 1 << (3 - Q);
#pragma unroll
  for (int i = 0; i < 16; ++i) if (!(i & m)) {
    const int j = i | m;
    float ar = vr[i], ai = vi[i], br = vr[j], bi = vi[j];
    vr[i] = c * ar - s * br; vi[i] = c * ai - s * bi;
    vr[j] = s * ar + c * br; vi[j] = s * ai + c * bi;
  }
}

// RX(theta): [[c,-i s],[-i s,c]]
template<int Q> DEVI void gRX(float* vr, float* vi, float c, float s) {
  constexpr int m = 1 << (3 - Q);
#pragma unroll
  for (int i = 0; i < 16; ++i) if (!(i & m)) {
    const int j = i | m;
    float ar = vr[i], ai = vi[i], br = vr[j], bi = vi[j];
    vr[i] = c * ar + s * bi; vi[i] = c * ai - s * br;
    vr[j] = c * br + s * ai; vi[j] = c * bi - s * ar;
  }
}

// RZ(theta): diag(c - i s, c + i s)
template<int Q> DEVI void gRZ(float* vr, float* vi, float c, float s) {
  constexpr int m = 1 << (3 - Q);
#pragma unroll
  for (int i = 0; i < 16; ++i) {
    float ar = vr[i], ai = vi[i];
    if (i & m) { vr[i] = c * ar - s * ai; vi[i] = c * ai + s * ar; }
    else       { vr[i] = c * ar + s * ai; vi[i] = c * ai - s * ar; }
  }
}

template<int C, int T> DEVI void gCNOT(float* vr, float* vi) {
  constexpr int mc = 1 << (3 - C), mt = 1 << (3 - T);
#pragma unroll
  for (int i = 0; i < 16; ++i) if ((i & mc) && !(i & mt)) {
    const int j = i | mt; float t;
    t = vr[i]; vr[i] = vr[j]; vr[j] = t;
    t = vi[i]; vi[i] = vi[j]; vi[j] = t;
  }
}

template<int A, int B2> DEVI void gCZ(float* vr, float* vi) {
  constexpr int ma = 1 << (3 - A), mb = 1 << (3 - B2);
#pragma unroll
  for (int i = 0; i < 16; ++i) if ((i & ma) && (i & mb)) { vr[i] = -vr[i]; vi[i] = -vi[i]; }
}

template<int C1, int C2, int T> DEVI void gTOF(float* vr, float* vi) {
  constexpr int m1 = 1 << (3 - C1), m2 = 1 << (3 - C2), mt = 1 << (3 - T);
#pragma unroll
  for (int i = 0; i < 16; ++i) if ((i & m1) && (i & m2) && !(i & mt)) {
    const int j = i | mt; float t;
    t = vr[i]; vr[i] = vr[j]; vr[j] = t;
    t = vi[i]; vi[i] = vi[j]; vi[j] = t;
  }
}

template<int C, int A, int B2> DEVI void gCSWAP(float* vr, float* vi) {
  constexpr int mc = 1 << (3 - C), ma = 1 << (3 - A), mb = 1 << (3 - B2);
#pragma unroll
  for (int i = 0; i < 16; ++i) if ((i & mc) && (i & ma) && !(i & mb)) {
    const int j = (i ^ ma) | mb; float t;
    t = vr[i]; vr[i] = vr[j]; vr[j] = t;
    t = vi[i]; vi[i] = vi[j]; vi[j] = t;
  }
}

// ---- prep: sin/cos of 0.5*w for the 24 batch-uniform rotations ----
__global__ void qprep(const float* __restrict__ q, float* __restrict__ wcs) {
  int k = threadIdx.x;
  if (k < 24) {
    float s, c;
    sincosf(0.5f * q[k], &s, &c);
    wcs[k] = c; wcs[24 + k] = s;
  }
}

// ---- main kernel: one thread per batch element ----
template<bool WSPRE>
__global__ __launch_bounds__(256)
void qsim(const float* __restrict__ x1, const float* __restrict__ x2,
          const float* __restrict__ q, const float* __restrict__ wcs,
          float* __restrict__ out, int B)
{
  const int b = blockIdx.x * blockDim.x + threadIdx.x;
  if (b >= B) return;

  float cw[24], sw[24];
  if constexpr (WSPRE) {
#pragma unroll
    for (int k = 0; k < 24; ++k) { cw[k] = wcs[k]; sw[k] = wcs[24 + k]; }
  } else {
#pragma unroll
    for (int k = 0; k < 24; ++k) sincosf(0.5f * q[k], &sw[k], &cw[k]);
  }

  const float4 xa = reinterpret_cast<const float4*>(x1)[b];
  const float4 xb = reinterpret_cast<const float4*>(x2)[b];
  float ca[4], sa[4], cb[4], sb[4];
  sincosf(0.5f * xa.x, &sa[0], &ca[0]);
  sincosf(0.5f * xa.y, &sa[1], &ca[1]);
  sincosf(0.5f * xa.z, &sa[2], &ca[2]);
  sincosf(0.5f * xa.w, &sa[3], &ca[3]);
  sincosf(0.5f * xb.x, &sb[0], &cb[0]);
  sincosf(0.5f * xb.y, &sb[1], &cb[1]);
  sincosf(0.5f * xb.z, &sb[2], &cb[2]);
  sincosf(0.5f * xb.w, &sb[3], &cb[3]);

  float vr[16], vi[16];
#pragma unroll
  for (int i = 0; i < 16; ++i) { vr[i] = 0.f; vi[i] = 0.f; }
  vr[0] = 1.f;

  // ================= forward run (x1, +theta) =================
  gH<0>(vr, vi); gH<1>(vr, vi); gH<2>(vr, vi); gH<3>(vr, vi);
  // l=0
  gRY<0>(vr, vi, ca[0], sa[0]); gRX<0>(vr, vi, cw[0],  sw[0]);  gH<0>(vr, vi);
  gRY<1>(vr, vi, cw[1], sw[1]); gX<1>(vr, vi);
  gRY<2>(vr, vi, ca[2], sa[2]); gRZ<2>(vr, vi, cw[2],  sw[2]);  gY<2>(vr, vi);
  gRX<3>(vr, vi, cw[3], sw[3]); gZ<3>(vr, vi);
  // l=1
  gRY<0>(vr, vi, cw[4], sw[4]); gCNOT<0,1>(vr, vi);
  gRY<1>(vr, vi, ca[1], sa[1]); gRZ<1>(vr, vi, cw[5],  sw[5]);  gCZ<1,2>(vr, vi);
  gRX<2>(vr, vi, cw[6], sw[6]); gTOF<2,3,0>(vr, vi);
  gRY<3>(vr, vi, ca[3], sa[3]); gRY<3>(vr, vi, cw[7],  sw[7]);  gCSWAP<3,0,1>(vr, vi);
  // l=2
  gRY<0>(vr, vi, ca[0], sa[0]); gRZ<0>(vr, vi, cw[8],  sw[8]);  gH<0>(vr, vi);
  gRX<1>(vr, vi, cw[9], sw[9]); gX<1>(vr, vi);
  gRY<2>(vr, vi, ca[2], sa[2]); gRY<2>(vr, vi, cw[10], sw[10]); gY<2>(vr, vi);
  gRZ<3>(vr, vi, cw[11], sw[11]); gZ<3>(vr, vi);
  // l=3
  gRX<0>(vr, vi, cw[12], sw[12]); gCNOT<0,1>(vr, vi);
  gRY<1>(vr, vi, ca[1], sa[1]); gRY<1>(vr, vi, cw[13], sw[13]); gCZ<1,2>(vr, vi);
  gRZ<2>(vr, vi, cw[14], sw[14]); gTOF<2,3,0>(vr, vi);
  gRY<3>(vr, vi, ca[3], sa[3]); gRX<3>(vr, vi, cw[15], sw[15]); gCSWAP<3,0,1>(vr, vi);
  // l=4
  gRY<0>(vr, vi, ca[0], sa[0]); gRY<0>(vr, vi, cw[16], sw[16]); gH<0>(vr, vi);
  gRZ<1>(vr, vi, cw[17], sw[17]); gX<1>(vr, vi);
  gRY<2>(vr, vi, ca[2], sa[2]); gRX<2>(vr, vi, cw[18], sw[18]); gY<2>(vr, vi);
  gRY<3>(vr, vi, cw[19], sw[19]); gZ<3>(vr, vi);
  // l=5
  gRZ<0>(vr, vi, cw[20], sw[20]); gCNOT<0,1>(vr, vi);
  gRY<1>(vr, vi, ca[1], sa[1]); gRX<1>(vr, vi, cw[21], sw[21]); gCZ<1,2>(vr, vi);
  gRY<2>(vr, vi, cw[22], sw[22]); gTOF<2,3,0>(vr, vi);
  gRY<3>(vr, vi, ca[3], sa[3]); gRZ<3>(vr, vi, cw[23], sw[23]); gCSWAP<3,0,1>(vr, vi);

  // ================= adjoint run (x2, -theta): reversed ops, sin negated =================
  // l=5 reversed
  gCSWAP<3,0,1>(vr, vi); gRZ<3>(vr, vi, cw[23], -sw[23]); gRY<3>(vr, vi, cb[3], -sb[3]);
  gTOF<2,3,0>(vr, vi);   gRY<2>(vr, vi, cw[22], -sw[22]);
  gCZ<1,2>(vr, vi);      gRX<1>(vr, vi, cw[21], -sw[21]); gRY<1>(vr, vi, cb[1], -sb[1]);
  gCNOT<0,1>(vr, vi);    gRZ<0>(vr, vi, cw[20], -sw[20]);
  // l=4 reversed
  gZ<3>(vr, vi); gRY<3>(vr, vi, cw[19], -sw[19]);
  gY<2>(vr, vi); gRX<2>(vr, vi, cw[18], -sw[18]); gRY<2>(vr, vi, cb[2], -sb[2]);
  gX<1>(vr, vi); gRZ<1>(vr, vi, cw[17], -sw[17]);
  gH<0>(vr, vi); gRY<0>(vr, vi, cw[16], -sw[16]); gRY<0>(vr, vi, cb[0], -sb[0]);
  // l=3 reversed
  gCSWAP<3,0,1>(vr, vi); gRX<3>(vr, vi, cw[15], -sw[15]); gRY<3>(vr, vi, cb[3], -sb[3]);
  gTOF<2,3,0>(vr, vi);   gRZ<2>(vr, vi, cw[14], -sw[14]);
  gCZ<1,2>(vr, vi);      gRY<1>(vr, vi, cw[13], -sw[13]); gRY<1>(vr, vi, cb[1], -sb[1]);
  gCNOT<0,1>(vr, vi);    gRX<0>(vr, vi, cw[12], -sw[12]);
  // l=2 reversed
  gZ<3>(vr, vi); gRZ<3>(vr, vi, cw[11], -sw[11]);
  gY<2>(vr, vi); gRY<2>(vr, vi, cw[10], -sw[10]); gRY<2>(vr, vi, cb[2], -sb[2]);
  gX<1>(vr, vi); gRX<1>(vr, vi, cw[9],  -sw[9]);
  gH<0>(vr, vi); gRZ<0>(vr, vi, cw[8],  -sw[8]);  gRY<0>(vr, vi, cb[0], -sb[0]);
  // l=1 reversed
  gCSWAP<3,0,1>(vr, vi); gRY<3>(vr, vi, cw[7], -sw[7]); gRY<3>(vr, vi, cb[3], -sb[3]);
  gTOF<2,3,0>(vr, vi);   gRX<2>(vr, vi, cw[6], -sw[6]);
  gCZ<1,2>(vr, vi);      gRZ<1>(vr, vi, cw[5], -sw[5]); gRY<1>(vr, vi, cb[1], -sb[1]);
  gCNOT<0,1>(vr, vi);    gRY<0>(vr, vi, cw[4], -sw[4]);
  // l=0 reversed
  gZ<3>(vr, vi); gRX<3>(vr, vi, cw[3], -sw[3]);
  gY<2>(vr, vi); gRZ<2>(vr, vi, cw[2], -sw[2]); gRY<2>(vr, vi, cb[2], -sb[2]);
  gX<1>(vr, vi); gRY<1>(vr, vi, cw[1], -sw[1]);
  gH<0>(vr, vi); gRX<0>(vr, vi, cw[0], -sw[0]); gRY<0>(vr, vi, cb[0], -sb[0]);
  // reversed initial Hadamards
  gH<3>(vr, vi); gH<2>(vr, vi); gH<1>(vr, vi); gH<0>(vr, vi);

  out[b] = vr[0] * vr[0] + vi[0] * vi[0];
}

extern "C" void kernel_launch(void* const* d_in, const int* in_sizes, int n_in,
                              void* d_out, int out_size, void* d_ws, size_t ws_size,
                              hipStream_t stream) {
  const float* x1 = (const float*)d_in[0];
  const float* x2 = (const float*)d_in[1];
  const float* q  = (const float*)d_in[2];
  float* out = (float*)d_out;
  const int B = in_sizes[0] / 4;
  const int block = 256;
  const int grid = (B + block - 1) / block;

  const bool use_ws = (d_ws != nullptr) && (ws_size >= 48 * sizeof(float));
  if (use_ws) {
    float* wcs = (float*)d_ws;
    qprep<<<1, 64, 0, stream>>>(q, wcs);
    qsim<true><<<grid, block, 0, stream>>>(x1, x2, q, wcs, out, B);
  } else {
    qsim<false><<<grid, block, 0, stream>>>(x1, x2, q, nullptr, out, B);
  }
}

// Round 3
// 85.150 us; speedup vs baseline: 1.1017x; 1.1017x over previous
//
#include <hip/hip_runtime.h>
#include <math.h>

// 4-qubit statevector simulator, circuit fully hardcoded from DESIGN.
// Qubit q corresponds to bit (3-q) of the state index (q=0 is MSB).
// State stored as float2 (re,im) per amplitude -> v_pk_fma_f32 packed fp32.

#define DEVI static __device__ __forceinline__

typedef float f2 __attribute__((ext_vector_type(2)));

DEVI f2 nI(f2 a) { f2 r; r.x = a.y; r.y = -a.x; return r; }   // -i * a
DEVI f2 pI(f2 a) { f2 r; r.x = -a.y; r.y = a.x; return r; }   // +i * a

// ---- gate helpers: all loops constant-bound, fully unrolled -> registers ----

template<int Q> DEVI void gH(f2* v) {
  constexpr int m = 1 << (3 - Q);
  const float K = 0.70710678118654752440f;
#pragma unroll
  for (int i = 0; i < 16; ++i) if (!(i & m)) {
    const int j = i | m;
    f2 a = v[i], b = v[j];
    v[i] = (a + b) * K;
    v[j] = (a - b) * K;
  }
}

template<int Q> DEVI void gX(f2* v) {
  constexpr int m = 1 << (3 - Q);
#pragma unroll
  for (int i = 0; i < 16; ++i) if (!(i & m)) {
    const int j = i | m;
    f2 t = v[i]; v[i] = v[j]; v[j] = t;
  }
}

template<int Q> DEVI void gY(f2* v) {
  constexpr int m = 1 << (3 - Q);
#pragma unroll
  for (int i = 0; i < 16; ++i) if (!(i & m)) {
    const int j = i | m;
    f2 a = v[i], b = v[j];
    v[i] = nI(b);   // -i*b
    v[j] = pI(a);   // +i*a
  }
}

template<int Q> DEVI void gZ(f2* v) {
  constexpr int m = 1 << (3 - Q);
#pragma unroll
  for (int i = 0; i < 16; ++i) if (i & m) v[i] = -v[i];
}

// RY(theta): [[c,-s],[s,c]]
template<int Q> DEVI void gRY(f2* v, float c, float s) {
  constexpr int m = 1 << (3 - Q);
#pragma unroll
  for (int i = 0; i < 16; ++i) if (!(i & m)) {
    const int j = i | m;
    f2 a = v[i], b = v[j];
    v[i] = a * c - b * s;
    v[j] = a * s + b * c;
  }
}

// RX(theta): [[c,-i s],[-i s,c]] : out_i = c*a + s*(-i b); out_j = c*b + s*(-i a)
template<int Q> DEVI void gRX(f2* v, float c, float s) {
  constexpr int m = 1 << (3 - Q);
#pragma unroll
  for (int i = 0; i < 16; ++i) if (!(i & m)) {
    const int j = i | m;
    f2 a = v[i], b = v[j];
    v[i] = a * c + nI(b) * s;
    v[j] = b * c + nI(a) * s;
  }
}

// RZ(theta): diag(c - i s, c + i s) : bit0 -> a*c + s*(-i a); bit1 -> a*c - s*(-i a)
template<int Q> DEVI void gRZ(f2* v, float c, float s) {
  constexpr int m = 1 << (3 - Q);
#pragma unroll
  for (int i = 0; i < 16; ++i) {
    f2 a = v[i];
    if (i & m) v[i] = a * c - nI(a) * s;
    else       v[i] = a * c + nI(a) * s;
  }
}

template<int C, int T> DEVI void gCNOT(f2* v) {
  constexpr int mc = 1 << (3 - C), mt = 1 << (3 - T);
#pragma unroll
  for (int i = 0; i < 16; ++i) if ((i & mc) && !(i & mt)) {
    const int j = i | mt;
    f2 t = v[i]; v[i] = v[j]; v[j] = t;
  }
}

template<int A, int B2> DEVI void gCZ(f2* v) {
  constexpr int ma = 1 << (3 - A), mb = 1 << (3 - B2);
#pragma unroll
  for (int i = 0; i < 16; ++i) if ((i & ma) && (i & mb)) v[i] = -v[i];
}

template<int C1, int C2, int T> DEVI void gTOF(f2* v) {
  constexpr int m1 = 1 << (3 - C1), m2 = 1 << (3 - C2), mt = 1 << (3 - T);
#pragma unroll
  for (int i = 0; i < 16; ++i) if ((i & m1) && (i & m2) && !(i & mt)) {
    const int j = i | mt;
    f2 t = v[i]; v[i] = v[j]; v[j] = t;
  }
}

template<int C, int A, int B2> DEVI void gCSWAP(f2* v) {
  constexpr int mc = 1 << (3 - C), ma = 1 << (3 - A), mb = 1 << (3 - B2);
#pragma unroll
  for (int i = 0; i < 16; ++i) if ((i & mc) && (i & ma) && !(i & mb)) {
    const int j = (i ^ ma) | mb;
    f2 t = v[i]; v[i] = v[j]; v[j] = t;
  }
}

DEVI float rlane(float v, int l) {
  return __int_as_float(__builtin_amdgcn_readlane(__float_as_int(v), l));
}

// ---- single fused kernel: one thread per batch element ----
__global__ __launch_bounds__(256)
void qsim(const float* __restrict__ x1, const float* __restrict__ x2,
          const float* __restrict__ q, float* __restrict__ out, int B)
{
  const int b = blockIdx.x * blockDim.x + threadIdx.x;
  if (b >= B) return;

  // Batch-uniform w sincos: lanes 0..23 each compute one angle, broadcast
  // via v_readlane into SGPR-resident coefficients.
  const int lane = threadIdx.x & 63;
  float qv = 0.f;
  if (lane < 24) qv = q[lane];
  float mys, myc;
  sincosf(0.5f * qv, &mys, &myc);
  float cw[24], sw[24];
#pragma unroll
  for (int k = 0; k < 24; ++k) { cw[k] = rlane(myc, k); sw[k] = rlane(mys, k); }

  const float4 xa = reinterpret_cast<const float4*>(x1)[b];
  const float4 xb = reinterpret_cast<const float4*>(x2)[b];
  float ca[4], sa[4], cb[4], sb[4];
  __sincosf(0.5f * xa.x, &sa[0], &ca[0]);
  __sincosf(0.5f * xa.y, &sa[1], &ca[1]);
  __sincosf(0.5f * xa.z, &sa[2], &ca[2]);
  __sincosf(0.5f * xa.w, &sa[3], &ca[3]);
  __sincosf(0.5f * xb.x, &sb[0], &cb[0]);
  __sincosf(0.5f * xb.y, &sb[1], &cb[1]);
  __sincosf(0.5f * xb.z, &sb[2], &cb[2]);
  __sincosf(0.5f * xb.w, &sb[3], &cb[3]);

  f2 v[16];
#pragma unroll
  for (int i = 0; i < 16; ++i) { v[i].x = 0.f; v[i].y = 0.f; }
  v[0].x = 1.f;

  // ================= forward run (x1, +theta) =================
  gH<0>(v); gH<1>(v); gH<2>(v); gH<3>(v);
  // l=0
  gRY<0>(v, ca[0], sa[0]); gRX<0>(v, cw[0],  sw[0]);  gH<0>(v);
  gRY<1>(v, cw[1], sw[1]); gX<1>(v);
  gRY<2>(v, ca[2], sa[2]); gRZ<2>(v, cw[2],  sw[2]);  gY<2>(v);
  gRX<3>(v, cw[3], sw[3]); gZ<3>(v);
  // l=1
  gRY<0>(v, cw[4], sw[4]); gCNOT<0,1>(v);
  gRY<1>(v, ca[1], sa[1]); gRZ<1>(v, cw[5],  sw[5]);  gCZ<1,2>(v);
  gRX<2>(v, cw[6], sw[6]); gTOF<2,3,0>(v);
  gRY<3>(v, ca[3], sa[3]); gRY<3>(v, cw[7],  sw[7]);  gCSWAP<3,0,1>(v);
  // l=2
  gRY<0>(v, ca[0], sa[0]); gRZ<0>(v, cw[8],  sw[8]);  gH<0>(v);
  gRX<1>(v, cw[9], sw[9]); gX<1>(v);
  gRY<2>(v, ca[2], sa[2]); gRY<2>(v, cw[10], sw[10]); gY<2>(v);
  gRZ<3>(v, cw[11], sw[11]); gZ<3>(v);
  // l=3
  gRX<0>(v, cw[12], sw[12]); gCNOT<0,1>(v);
  gRY<1>(v, ca[1], sa[1]); gRY<1>(v, cw[13], sw[13]); gCZ<1,2>(v);
  gRZ<2>(v, cw[14], sw[14]); gTOF<2,3,0>(v);
  gRY<3>(v, ca[3], sa[3]); gRX<3>(v, cw[15], sw[15]); gCSWAP<3,0,1>(v);
  // l=4
  gRY<0>(v, ca[0], sa[0]); gRY<0>(v, cw[16], sw[16]); gH<0>(v);
  gRZ<1>(v, cw[17], sw[17]); gX<1>(v);
  gRY<2>(v, ca[2], sa[2]); gRX<2>(v, cw[18], sw[18]); gY<2>(v);
  gRY<3>(v, cw[19], sw[19]); gZ<3>(v);
  // l=5
  gRZ<0>(v, cw[20], sw[20]); gCNOT<0,1>(v);
  gRY<1>(v, ca[1], sa[1]); gRX<1>(v, cw[21], sw[21]); gCZ<1,2>(v);
  gRY<2>(v, cw[22], sw[22]); gTOF<2,3,0>(v);
  gRY<3>(v, ca[3], sa[3]); gRZ<3>(v, cw[23], sw[23]); gCSWAP<3,0,1>(v);

  // ======== adjoint run (x2, -theta): reversed ops, sin negated ========
  // l=5 reversed
  gCSWAP<3,0,1>(v); gRZ<3>(v, cw[23], -sw[23]); gRY<3>(v, cb[3], -sb[3]);
  gTOF<2,3,0>(v);   gRY<2>(v, cw[22], -sw[22]);
  gCZ<1,2>(v);      gRX<1>(v, cw[21], -sw[21]); gRY<1>(v, cb[1], -sb[1]);
  gCNOT<0,1>(v);    gRZ<0>(v, cw[20], -sw[20]);
  // l=4 reversed
  gZ<3>(v); gRY<3>(v, cw[19], -sw[19]);
  gY<2>(v); gRX<2>(v, cw[18], -sw[18]); gRY<2>(v, cb[2], -sb[2]);
  gX<1>(v); gRZ<1>(v, cw[17], -sw[17]);
  gH<0>(v); gRY<0>(v, cw[16], -sw[16]); gRY<0>(v, cb[0], -sb[0]);
  // l=3 reversed
  gCSWAP<3,0,1>(v); gRX<3>(v, cw[15], -sw[15]); gRY<3>(v, cb[3], -sb[3]);
  gTOF<2,3,0>(v);   gRZ<2>(v, cw[14], -sw[14]);
  gCZ<1,2>(v);      gRY<1>(v, cw[13], -sw[13]); gRY<1>(v, cb[1], -sb[1]);
  gCNOT<0,1>(v);    gRX<0>(v, cw[12], -sw[12]);
  // l=2 reversed
  gZ<3>(v); gRZ<3>(v, cw[11], -sw[11]);
  gY<2>(v); gRY<2>(v, cw[10], -sw[10]); gRY<2>(v, cb[2], -sb[2]);
  gX<1>(v); gRX<1>(v, cw[9],  -sw[9]);
  gH<0>(v); gRZ<0>(v, cw[8],  -sw[8]);  gRY<0>(v, cb[0], -sb[0]);
  // l=1 reversed
  gCSWAP<3,0,1>(v); gRY<3>(v, cw[7], -sw[7]); gRY<3>(v, cb[3], -sb[3]);
  gTOF<2,3,0>(v);   gRX<2>(v, cw[6], -sw[6]);
  gCZ<1,2>(v);      gRZ<1>(v, cw[5], -sw[5]); gRY<1>(v, cb[1], -sb[1]);
  gCNOT<0,1>(v);    gRY<0>(v, cw[4], -sw[4]);
  // l=0 reversed
  gZ<3>(v); gRX<3>(v, cw[3], -sw[3]);
  gY<2>(v); gRZ<2>(v, cw[2], -sw[2]); gRY<2>(v, cb[2], -sb[2]);
  gX<1>(v); gRY<1>(v, cw[1], -sw[1]);
  gH<0>(v); gRX<0>(v, cw[0], -sw[0]); gRY<0>(v, cb[0], -sb[0]);
  // reversed initial Hadamards
  gH<3>(v); gH<2>(v); gH<1>(v); gH<0>(v);

  f2 a0 = v[0];
  out[b] = a0.x * a0.x + a0.y * a0.y;
}

extern "C" void kernel_launch(void* const* d_in, const int* in_sizes, int n_in,
                              void* d_out, int out_size, void* d_ws, size_t ws_size,
                              hipStream_t stream) {
  const float* x1 = (const float*)d_in[0];
  const float* x2 = (const float*)d_in[1];
  const float* q  = (const float*)d_in[2];
  float* out = (float*)d_out;
  const int B = in_sizes[0] / 4;
  const int block = 256;
  const int grid = (B + block - 1) / block;
  qsim<<<grid, block, 0, stream>>>(x1, x2, q, out, B);
}

// Round 4
// 81.000 us; speedup vs baseline: 1.1582x; 1.0512x over previous
//
#include <hip/hip_runtime.h>
#include <math.h>

// out = |<psi(x2), psi(x1)>|^2 where psi(x) = U(x,w)|0> (forward circuit only).
// 4-qubit statevector; qubit q = bit (3-q) of state index. State = f2 (re,im)
// per amplitude -> packed fp32 (v_pk_*_f32). Circuit hardcoded from DESIGN
// with batch-uniform composites (H*R, Y*R, Z-folds) precomputed per thread.

#define DEVI static __device__ __forceinline__

typedef float f2 __attribute__((ext_vector_type(2)));

DEVI f2 nI(f2 a) { f2 r; r.x = a.y;  r.y = -a.x; return r; }   // -i * a
DEVI f2 pI(f2 a) { f2 r; r.x = -a.y; r.y = a.x;  return r; }   // +i * a
// complex multiply by constant g: a*g = g.x*a + g.y*(i*a)
DEVI f2 cmul(f2 a, f2 g) { return a * g.x + pI(a) * g.y; }

// ---------------- gate helpers (one 16-amp state) ----------------

template<int Q> DEVI void gH(f2* v) {
  constexpr int m = 1 << (3 - Q);
  const float K = 0.70710678118654752440f;
#pragma unroll
  for (int i = 0; i < 16; ++i) if (!(i & m)) {
    const int j = i | m;
    f2 a = v[i], b = v[j];
    v[i] = (a + b) * K;
    v[j] = (a - b) * K;
  }
}

template<int Q> DEVI void gX(f2* v) {
  constexpr int m = 1 << (3 - Q);
#pragma unroll
  for (int i = 0; i < 16; ++i) if (!(i & m)) {
    const int j = i | m;
    f2 t = v[i]; v[i] = v[j]; v[j] = t;
  }
}

template<int Q> DEVI void gY(f2* v) {
  constexpr int m = 1 << (3 - Q);
#pragma unroll
  for (int i = 0; i < 16; ++i) if (!(i & m)) {
    const int j = i | m;
    f2 a = v[i], b = v[j];
    v[i] = nI(b);
    v[j] = pI(a);
  }
}

// RY(t): [[c,-s],[s,c]]
template<int Q> DEVI void gRY(f2* v, float c, float s) {
  constexpr int m = 1 << (3 - Q);
#pragma unroll
  for (int i = 0; i < 16; ++i) if (!(i & m)) {
    const int j = i | m;
    f2 a = v[i], b = v[j];
    v[i] = a * c - b * s;
    v[j] = a * s + b * c;
  }
}

// RX(t): [[c,-is],[-is,c]]
template<int Q> DEVI void gRX(f2* v, float c, float s) {
  constexpr int m = 1 << (3 - Q);
#pragma unroll
  for (int i = 0; i < 16; ++i) if (!(i & m)) {
    const int j = i | m;
    f2 a = v[i], b = v[j];
    v[i] = a * c + nI(b) * s;
    v[j] = b * c + nI(a) * s;
  }
}

// RZ(t): diag(c-is, c+is)
template<int Q> DEVI void gRZ(f2* v, float c, float s) {
  constexpr int m = 1 << (3 - Q);
#pragma unroll
  for (int i = 0; i < 16; ++i) {
    f2 a = v[i];
    if (i & m) v[i] = a * c + pI(a) * s;
    else       v[i] = a * c - pI(a) * s;
  }
}

// ---- fused composites (matrix = FIX * ROT, applied after any RY(x)) ----

// H*RY(phi) = K[[c+s, c-s],[c-s, -(c+s)]] (real)
template<int Q> DEVI void gHRY(f2* v, float c, float s) {
  constexpr int m = 1 << (3 - Q);
  const float K = 0.70710678118654752440f;
  const float al = K * (c + s), be = K * (c - s);
#pragma unroll
  for (int i = 0; i < 16; ++i) if (!(i & m)) {
    const int j = i | m;
    f2 a = v[i], b = v[j];
    v[i] = a * al + b * be;
    v[j] = a * be - b * al;
  }
}

// H*RX(w) = [[Em,Em],[Ep,-Ep]], Em=K(c-is), Ep=K(c+is)
template<int Q> DEVI void gHRX(f2* v, f2 Em, f2 Ep) {
  constexpr int m = 1 << (3 - Q);
#pragma unroll
  for (int i = 0; i < 16; ++i) if (!(i & m)) {
    const int j = i | m;
    f2 a = v[i], b = v[j];
    f2 t = a + b, u = a - b;
    v[i] = cmul(t, Em);
    v[j] = cmul(u, Ep);
  }
}

// H*RZ(w) = [[Em,Ep],[Em,-Ep]], Em=K(c-is), Ep=K(c+is)
template<int Q> DEVI void gHRZ(f2* v, f2 Em, f2 Ep) {
  constexpr int m = 1 << (3 - Q);
#pragma unroll
  for (int i = 0; i < 16; ++i) if (!(i & m)) {
    const int j = i | m;
    f2 a = v[i], b = v[j];
    f2 p = cmul(a, Em), q = cmul(b, Ep);
    v[i] = p + q;
    v[j] = p - q;
  }
}

// Y*RZ(w) = [[0, G1],[G2, 0]], G1=-i(c+is)=(s,-c), G2=i(c-is)=(s,c)
template<int Q> DEVI void gYRZ(f2* v, f2 G1, f2 G2) {
  constexpr int m = 1 << (3 - Q);
#pragma unroll
  for (int i = 0; i < 16; ++i) if (!(i & m)) {
    const int j = i | m;
    f2 a = v[i], b = v[j];
    v[i] = cmul(b, G1);
    v[j] = cmul(a, G2);
  }
}

// Y*RX(w): out_i = -s*a + c*(-i b); out_j = c*(i a) + s*b
template<int Q> DEVI void gYRX(f2* v, float c, float s) {
  constexpr int m = 1 << (3 - Q);
#pragma unroll
  for (int i = 0; i < 16; ++i) if (!(i & m)) {
    const int j = i | m;
    f2 a = v[i], b = v[j];
    v[i] = nI(b) * c - a * s;
    v[j] = pI(a) * c + b * s;
  }
}

// Z*RX(w): out_i = c*a + s*(-i b); out_j = s*(i a) - c*b
template<int Q> DEVI void gZRX(f2* v, float c, float s) {
  constexpr int m = 1 << (3 - Q);
#pragma unroll
  for (int i = 0; i < 16; ++i) if (!(i & m)) {
    const int j = i | m;
    f2 a = v[i], b = v[j];
    v[i] = a * c + nI(b) * s;
    v[j] = pI(a) * s - b * c;
  }
}

// Z*RZ(w): bit0 -> a*(c-is); bit1 -> a*(-c-is)
template<int Q> DEVI void gZRZ(f2* v, float c, float s) {
  constexpr int m = 1 << (3 - Q);
#pragma unroll
  for (int i = 0; i < 16; ++i) {
    f2 a = v[i];
    if (i & m) v[i] = pI(a) * (-s) - a * c;
    else       v[i] = a * c - pI(a) * s;
  }
}

// Z*RY(w): out_i = c*a - s*b; out_j = -s*a - c*b
template<int Q> DEVI void gZRY(f2* v, float c, float s) {
  constexpr int m = 1 << (3 - Q);
#pragma unroll
  for (int i = 0; i < 16; ++i) if (!(i & m)) {
    const int j = i | m;
    f2 a = v[i], b = v[j];
    v[i] = a * c - b * s;
    v[j] = a * (-s) - b * c;
  }
}

template<int A, int B2> DEVI void gCZ(f2* v) {
  constexpr int ma = 1 << (3 - A), mb = 1 << (3 - B2);
#pragma unroll
  for (int i = 0; i < 16; ++i) if ((i & ma) && (i & mb)) v[i] = -v[i];
}

template<int C, int T> DEVI void gCNOT(f2* v) {
  constexpr int mc = 1 << (3 - C), mt = 1 << (3 - T);
#pragma unroll
  for (int i = 0; i < 16; ++i) if ((i & mc) && !(i & mt)) {
    const int j = i | mt;
    f2 t = v[i]; v[i] = v[j]; v[j] = t;
  }
}

template<int C1, int C2, int T> DEVI void gTOF(f2* v) {
  constexpr int m1 = 1 << (3 - C1), m2 = 1 << (3 - C2), mt = 1 << (3 - T);
#pragma unroll
  for (int i = 0; i < 16; ++i) if ((i & m1) && (i & m2) && !(i & mt)) {
    const int j = i | mt;
    f2 t = v[i]; v[i] = v[j]; v[j] = t;
  }
}

template<int C, int A, int B2> DEVI void gCSWAP(f2* v) {
  constexpr int mc = 1 << (3 - C), ma = 1 << (3 - A), mb = 1 << (3 - B2);
#pragma unroll
  for (int i = 0; i < 16; ++i) if ((i & mc) && (i & ma) && !(i & mb)) {
    const int j = (i ^ ma) | mb;
    f2 t = v[i]; v[i] = v[j]; v[j] = t;
  }
}

struct Uni {
  float cw[24], sw[24];
  f2 Em0, Ep0;   // H*RX(w0)
  f2 G1_2, G2_2; // Y*RZ(w2)
  f2 Em8, Ep8;   // H*RZ(w8)
};

// forward circuit: v starts at H^4|0> = uniform 1/4
DEVI void fwd(f2* v, const float* cx, const float* sx, const Uni& U) {
  const float* cw = U.cw; const float* sw = U.sw;
  // fused RY(x)*RY(w) half-angle sums at l+n==4 sites
  const float c73  = cx[3]*cw[7]  - sx[3]*sw[7],  s73  = sx[3]*cw[7]  + cx[3]*sw[7];
  const float c102 = cx[2]*cw[10] - sx[2]*sw[10], s102 = sx[2]*cw[10] + cx[2]*sw[10];
  const float c131 = cx[1]*cw[13] - sx[1]*sw[13], s131 = sx[1]*cw[13] + cx[1]*sw[13];
  const float c160 = cx[0]*cw[16] - sx[0]*sw[16], s160 = sx[0]*cw[16] + cx[0]*sw[16];

  // l=0
  gRY<0>(v, cx[0], sx[0]); gHRX<0>(v, U.Em0, U.Ep0);
  gRY<1>(v, cw[1], sw[1]); gX<1>(v);
  gRY<2>(v, cx[2], sx[2]); gYRZ<2>(v, U.G1_2, U.G2_2);
  gZRX<3>(v, cw[3], sw[3]);
  // l=1
  gRY<0>(v, cw[4], sw[4]); gCNOT<0,1>(v);
  gRY<1>(v, cx[1], sx[1]); gRZ<1>(v, cw[5], sw[5]); gCZ<1,2>(v);
  gRX<2>(v, cw[6], sw[6]); gTOF<2,3,0>(v);
  gRY<3>(v, c73, s73);     gCSWAP<3,0,1>(v);
  // l=2
  gRY<0>(v, cx[0], sx[0]); gHRZ<0>(v, U.Em8, U.Ep8);
  gRX<1>(v, cw[9], sw[9]); gX<1>(v);
  gRY<2>(v, c102, s102);   gY<2>(v);
  gZRZ<3>(v, cw[11], sw[11]);
  // l=3
  gRX<0>(v, cw[12], sw[12]); gCNOT<0,1>(v);
  gRY<1>(v, c131, s131);     gCZ<1,2>(v);
  gRZ<2>(v, cw[14], sw[14]); gTOF<2,3,0>(v);
  gRY<3>(v, cx[3], sx[3]); gRX<3>(v, cw[15], sw[15]); gCSWAP<3,0,1>(v);
  // l=4
  gHRY<0>(v, c160, s160);
  gRZ<1>(v, cw[17], sw[17]); gX<1>(v);
  gRY<2>(v, cx[2], sx[2]); gYRX<2>(v, cw[18], sw[18]);
  gZRY<3>(v, cw[19], sw[19]);
  // l=5
  gRZ<0>(v, cw[20], sw[20]); gCNOT<0,1>(v);
  gRY<1>(v, cx[1], sx[1]); gRX<1>(v, cw[21], sw[21]); gCZ<1,2>(v);
  gRY<2>(v, cw[22], sw[22]); gTOF<2,3,0>(v);
  gRY<3>(v, cx[3], sx[3]); gRZ<3>(v, cw[23], sw[23]); gCSWAP<3,0,1>(v);
}

DEVI float rlane(float v, int l) {
  return __int_as_float(__builtin_amdgcn_readlane(__float_as_int(v), l));
}

__global__ __launch_bounds__(256, 4)
void qsim(const float* __restrict__ x1, const float* __restrict__ x2,
          const float* __restrict__ q, float* __restrict__ out, int B)
{
  const int b = blockIdx.x * blockDim.x + threadIdx.x;
  if (b >= B) return;

  // batch-uniform w sincos: lanes 0..23 compute, broadcast via readlane
  const int lane = threadIdx.x & 63;
  float qv = 0.f;
  if (lane < 24) qv = q[lane];
  float mys, myc;
  __sincosf(0.5f * qv, &mys, &myc);

  Uni U;
#pragma unroll
  for (int k = 0; k < 24; ++k) { U.cw[k] = rlane(myc, k); U.sw[k] = rlane(mys, k); }
  const float K = 0.70710678118654752440f;
  U.Em0.x  = K * U.cw[0]; U.Em0.y  = -K * U.sw[0];
  U.Ep0.x  = K * U.cw[0]; U.Ep0.y  =  K * U.sw[0];
  U.G1_2.x = U.sw[2];     U.G1_2.y = -U.cw[2];
  U.G2_2.x = U.sw[2];     U.G2_2.y =  U.cw[2];
  U.Em8.x  = K * U.cw[8]; U.Em8.y  = -K * U.sw[8];
  U.Ep8.x  = K * U.cw[8]; U.Ep8.y  =  K * U.sw[8];

  const float4 xa = reinterpret_cast<const float4*>(x1)[b];
  const float4 xb = reinterpret_cast<const float4*>(x2)[b];
  float ca[4], sa[4], cb[4], sb[4];
  __sincosf(0.5f * xa.x, &sa[0], &ca[0]);
  __sincosf(0.5f * xa.y, &sa[1], &ca[1]);
  __sincosf(0.5f * xa.z, &sa[2], &ca[2]);
  __sincosf(0.5f * xa.w, &sa[3], &ca[3]);
  __sincosf(0.5f * xb.x, &sb[0], &cb[0]);
  __sincosf(0.5f * xb.y, &sb[1], &cb[1]);
  __sincosf(0.5f * xb.z, &sb[2], &cb[2]);
  __sincosf(0.5f * xb.w, &sb[3], &cb[3]);

  // both states start at H^4|0> = uniform 1/4
  f2 vA[16], vB[16];
#pragma unroll
  for (int i = 0; i < 16; ++i) { vA[i].x = 0.25f; vA[i].y = 0.f; vB[i].x = 0.25f; vB[i].y = 0.f; }

  fwd(vA, ca, sa, U);
  fwd(vB, cb, sb, U);

  // out = |<vB, vA>|^2 = |sum conj(vB_i) * vA_i|^2
  float re = 0.f, im = 0.f;
#pragma unroll
  for (int i = 0; i < 16; ++i) {
    re += vB[i].x * vA[i].x + vB[i].y * vA[i].y;
    im += vB[i].x * vA[i].y - vB[i].y * vA[i].x;
  }
  out[b] = re * re + im * im;
}

extern "C" void kernel_launch(void* const* d_in, const int* in_sizes, int n_in,
                              void* d_out, int out_size, void* d_ws, size_t ws_size,
                              hipStream_t stream) {
  const float* x1 = (const float*)d_in[0];
  const float* x2 = (const float*)d_in[1];
  const float* q  = (const float*)d_in[2];
  float* out = (float*)d_out;
  const int B = in_sizes[0] / 4;
  const int block = 256;
  const int grid = (B + block - 1) / block;
  qsim<<<grid, block, 0, stream>>>(x1, x2, q, out, B);
}

// Round 5
// 78.664 us; speedup vs baseline: 1.1926x; 1.0297x over previous
//
#include <hip/hip_runtime.h>
#include <math.h>

// out = |<psi(x2), psi(x1)>|^2, psi(x) = U(x,w)|0> (forward circuit only).
// 4-qubit statevector; qubit q = bit (3-q). State = f2 (re,im) per amplitude.
// All butterflies written as explicit packed fma (__builtin_elementwise_fma on
// <2 x float>) -> v_pk_mul_f32 / v_pk_fma_f32. Complex uniform coefficients
// pass both g and i*g so no variable shuffles are needed in cmul.

#define DEVI static __device__ __forceinline__

typedef float f2 __attribute__((ext_vector_type(2)));

DEVI f2 sp(float x) { f2 r; r.x = x; r.y = x; return r; }
DEVI f2 mk(float x, float y) { f2 r; r.x = x; r.y = y; return r; }
DEVI f2 fm(f2 a, f2 b, f2 c) { return __builtin_elementwise_fma(a, b, c); }
DEVI f2 nI(f2 a) { f2 r; r.x = a.y;  r.y = -a.x; return r; }   // -i*a
DEVI f2 pI(f2 a) { f2 r; r.x = -a.y; r.y = a.x;  return r; }   // +i*a
// a * g for uniform complex g, with ig = i*g precomputed: 2 packed insts
DEVI f2 cmulc(f2 a, f2 g, f2 ig) { return fm(sp(a.y), ig, sp(a.x) * g); }

// ---------------- gate helpers (one 16-amp state) ----------------

template<int Q> DEVI void gX(f2* v) {
  constexpr int m = 1 << (3 - Q);
#pragma unroll
  for (int i = 0; i < 16; ++i) if (!(i & m)) {
    const int j = i | m; f2 t = v[i]; v[i] = v[j]; v[j] = t;
  }
}

// RY(t): [[c,-s],[s,c]]
template<int Q> DEVI void gRY(f2* v, float c, float s) {
  constexpr int m = 1 << (3 - Q);
  const f2 C = sp(c), S = sp(s), NS = sp(-s);
#pragma unroll
  for (int i = 0; i < 16; ++i) if (!(i & m)) {
    const int j = i | m;
    f2 a = v[i], b = v[j];
    v[i] = fm(b, NS, a * C);
    v[j] = fm(b, C,  a * S);
  }
}

// RX(t): [[c,-is],[-is,c]]
template<int Q> DEVI void gRX(f2* v, float c, float s) {
  constexpr int m = 1 << (3 - Q);
  const f2 C = sp(c), S = sp(s);
#pragma unroll
  for (int i = 0; i < 16; ++i) if (!(i & m)) {
    const int j = i | m;
    f2 a = v[i], b = v[j];
    v[i] = fm(nI(b), S, a * C);
    v[j] = fm(nI(a), S, b * C);
  }
}

// RZ(t) uniform: diag(c-is, c+is)
template<int Q> DEVI void gRZ(f2* v, float c, float s) {
  constexpr int m = 1 << (3 - Q);
  const f2 g0 = mk(c, -s), ig0 = mk(s, c);
  const f2 g1 = mk(c,  s), ig1 = mk(-s, c);
#pragma unroll
  for (int i = 0; i < 16; ++i) {
    f2 a = v[i];
    v[i] = (i & m) ? cmulc(a, g1, ig1) : cmulc(a, g0, ig0);
  }
}

// H*RX(w): [[Em,Em],[Ep,-Ep]]
template<int Q> DEVI void gHRX(f2* v, f2 Em, f2 Ep, f2 iEm, f2 iEp) {
  constexpr int m = 1 << (3 - Q);
#pragma unroll
  for (int i = 0; i < 16; ++i) if (!(i & m)) {
    const int j = i | m;
    f2 a = v[i], b = v[j];
    f2 t = a + b, u = a - b;
    v[i] = cmulc(t, Em, iEm);
    v[j] = cmulc(u, Ep, iEp);
  }
}

// H*RZ(w): [[Em,Ep],[Em,-Ep]]
template<int Q> DEVI void gHRZ(f2* v, f2 Em, f2 Ep, f2 iEm, f2 iEp) {
  constexpr int m = 1 << (3 - Q);
#pragma unroll
  for (int i = 0; i < 16; ++i) if (!(i & m)) {
    const int j = i | m;
    f2 a = v[i], b = v[j];
    f2 p = cmulc(a, Em, iEm), q = cmulc(b, Ep, iEp);
    v[i] = p + q;
    v[j] = p - q;
  }
}

// Y*RZ(w): [[0,G1],[G2,0]]
template<int Q> DEVI void gYRZ(f2* v, f2 G1, f2 G2, f2 iG1, f2 iG2) {
  constexpr int m = 1 << (3 - Q);
#pragma unroll
  for (int i = 0; i < 16; ++i) if (!(i & m)) {
    const int j = i | m;
    f2 a = v[i], b = v[j];
    v[i] = cmulc(b, G1, iG1);
    v[j] = cmulc(a, G2, iG2);
  }
}

// Y*RX(w): out_i = -s*a + c*(-i b); out_j = c*(i a) + s*b
template<int Q> DEVI void gYRX(f2* v, float c, float s) {
  constexpr int m = 1 << (3 - Q);
  const f2 C = sp(c), S = sp(s), NS = sp(-s);
#pragma unroll
  for (int i = 0; i < 16; ++i) if (!(i & m)) {
    const int j = i | m;
    f2 a = v[i], b = v[j];
    v[i] = fm(nI(b), C, a * NS);
    v[j] = fm(pI(a), C, b * S);
  }
}

// Z*RX(w): out_i = c*a + s*(-i b); out_j = s*(i a) - c*b
template<int Q> DEVI void gZRX(f2* v, float c, float s) {
  constexpr int m = 1 << (3 - Q);
  const f2 C = sp(c), S = sp(s), NC = sp(-c);
#pragma unroll
  for (int i = 0; i < 16; ++i) if (!(i & m)) {
    const int j = i | m;
    f2 a = v[i], b = v[j];
    v[i] = fm(nI(b), S, a * C);
    v[j] = fm(pI(a), S, b * NC);
  }
}

// Z*RZ(w): bit0 -> a*(c-is); bit1 -> a*(-c-is)
template<int Q> DEVI void gZRZ(f2* v, float c, float s) {
  constexpr int m = 1 << (3 - Q);
  const f2 g0 = mk(c, -s),  ig0 = mk(s, c);
  const f2 g1 = mk(-c, -s), ig1 = mk(s, -c);
#pragma unroll
  for (int i = 0; i < 16; ++i) {
    f2 a = v[i];
    v[i] = (i & m) ? cmulc(a, g1, ig1) : cmulc(a, g0, ig0);
  }
}

// Z*RY(w): out_i = c*a - s*b; out_j = -s*a - c*b
template<int Q> DEVI void gZRY(f2* v, float c, float s) {
  constexpr int m = 1 << (3 - Q);
  const f2 C = sp(c), NS = sp(-s), NC = sp(-c);
#pragma unroll
  for (int i = 0; i < 16; ++i) if (!(i & m)) {
    const int j = i | m;
    f2 a = v[i], b = v[j];
    v[i] = fm(b, NS, a * C);
    v[j] = fm(b, NC, a * NS);
  }
}

// H*RY(phi): K[[c+s, c-s],[c-s, -(c+s)]]
template<int Q> DEVI void gHRY(f2* v, float c, float s) {
  constexpr int m = 1 << (3 - Q);
  const float K = 0.70710678118654752440f;
  const float al = K * (c + s), be = K * (c - s);
  const f2 AL = sp(al), BE = sp(be), NAL = sp(-al);
#pragma unroll
  for (int i = 0; i < 16; ++i) if (!(i & m)) {
    const int j = i | m;
    f2 a = v[i], b = v[j];
    v[i] = fm(b, BE,  a * AL);
    v[j] = fm(b, NAL, a * BE);
  }
}

// Y*RY(phi): out_i = -i(s*a + c*b); out_j = i(c*a - s*b)
template<int Q> DEVI void gYRY(f2* v, float c, float s) {
  constexpr int m = 1 << (3 - Q);
  const f2 C = sp(c), S = sp(s), NS = sp(-s);
#pragma unroll
  for (int i = 0; i < 16; ++i) if (!(i & m)) {
    const int j = i | m;
    f2 a = v[i], b = v[j];
    f2 t = fm(b, C, a * S);
    f2 u = fm(b, NS, a * C);
    v[i] = nI(t);
    v[j] = pI(u);
  }
}

template<int A, int B2> DEVI void gCZ(f2* v) {
  constexpr int ma = 1 << (3 - A), mb = 1 << (3 - B2);
#pragma unroll
  for (int i = 0; i < 16; ++i) if ((i & ma) && (i & mb)) v[i] = -v[i];
}

template<int C, int T> DEVI void gCNOT(f2* v) {
  constexpr int mc = 1 << (3 - C), mt = 1 << (3 - T);
#pragma unroll
  for (int i = 0; i < 16; ++i) if ((i & mc) && !(i & mt)) {
    const int j = i | mt; f2 t = v[i]; v[i] = v[j]; v[j] = t;
  }
}

template<int C1, int C2, int T> DEVI void gTOF(f2* v) {
  constexpr int m1 = 1 << (3 - C1), m2 = 1 << (3 - C2), mt = 1 << (3 - T);
#pragma unroll
  for (int i = 0; i < 16; ++i) if ((i & m1) && (i & m2) && !(i & mt)) {
    const int j = i | mt; f2 t = v[i]; v[i] = v[j]; v[j] = t;
  }
}

template<int C, int A, int B2> DEVI void gCSWAP(f2* v) {
  constexpr int mc = 1 << (3 - C), ma = 1 << (3 - A), mb = 1 << (3 - B2);
#pragma unroll
  for (int i = 0; i < 16; ++i) if ((i & mc) && (i & ma) && !(i & mb)) {
    const int j = (i ^ ma) | mb; f2 t = v[i]; v[i] = v[j]; v[j] = t;
  }
}

// forward circuit: v starts at H^4|0> = uniform 1/4
DEVI void fwd(f2* v, const float* cx, const float* sx,
              const float* cw, const float* sw) {
  const float K = 0.70710678118654752440f;
  // uniform composite constants (CSE'd across both fwd calls)
  const f2 Em0  = mk(K*cw[0], -K*sw[0]), Ep0  = mk(K*cw[0],  K*sw[0]);
  const f2 iEm0 = mk(K*sw[0],  K*cw[0]), iEp0 = mk(-K*sw[0], K*cw[0]);
  const f2 G1   = mk(sw[2], -cw[2]),     G2   = mk(sw[2],  cw[2]);
  const f2 iG1  = mk(cw[2],  sw[2]),     iG2  = mk(-cw[2], sw[2]);
  const f2 Em8  = mk(K*cw[8], -K*sw[8]), Ep8  = mk(K*cw[8],  K*sw[8]);
  const f2 iEm8 = mk(K*sw[8],  K*cw[8]), iEp8 = mk(-K*sw[8], K*cw[8]);
  // fused RY(x)*RY(w) half-angle sums at l+n==4 sites
  const float c73  = cx[3]*cw[7]  - sx[3]*sw[7],  s73  = sx[3]*cw[7]  + cx[3]*sw[7];
  const float c102 = cx[2]*cw[10] - sx[2]*sw[10], s102 = sx[2]*cw[10] + cx[2]*sw[10];
  const float c131 = cx[1]*cw[13] - sx[1]*sw[13], s131 = sx[1]*cw[13] + cx[1]*sw[13];
  const float c160 = cx[0]*cw[16] - sx[0]*sw[16], s160 = sx[0]*cw[16] + cx[0]*sw[16];

  // l=0
  gRY<0>(v, cx[0], sx[0]); gHRX<0>(v, Em0, Ep0, iEm0, iEp0);
  gRY<1>(v, cw[1], sw[1]); gX<1>(v);
  gRY<2>(v, cx[2], sx[2]); gYRZ<2>(v, G1, G2, iG1, iG2);
  gZRX<3>(v, cw[3], sw[3]);
  // l=1
  gRY<0>(v, cw[4], sw[4]); gCNOT<0,1>(v);
  gRY<1>(v, cx[1], sx[1]); gRZ<1>(v, cw[5], sw[5]); gCZ<1,2>(v);
  gRX<2>(v, cw[6], sw[6]); gTOF<2,3,0>(v);
  gRY<3>(v, c73, s73);     gCSWAP<3,0,1>(v);
  // l=2
  gRY<0>(v, cx[0], sx[0]); gHRZ<0>(v, Em8, Ep8, iEm8, iEp8);
  gRX<1>(v, cw[9], sw[9]); gX<1>(v);
  gYRY<2>(v, c102, s102);
  gZRZ<3>(v, cw[11], sw[11]);
  // l=3
  gRX<0>(v, cw[12], sw[12]); gCNOT<0,1>(v);
  gRY<1>(v, c131, s131);     gCZ<1,2>(v);
  gRZ<2>(v, cw[14], sw[14]); gTOF<2,3,0>(v);
  gRY<3>(v, cx[3], sx[3]); gRX<3>(v, cw[15], sw[15]); gCSWAP<3,0,1>(v);
  // l=4
  gHRY<0>(v, c160, s160);
  gRZ<1>(v, cw[17], sw[17]); gX<1>(v);
  gRY<2>(v, cx[2], sx[2]); gYRX<2>(v, cw[18], sw[18]);
  gZRY<3>(v, cw[19], sw[19]);
  // l=5
  gRZ<0>(v, cw[20], sw[20]); gCNOT<0,1>(v);
  gRY<1>(v, cx[1], sx[1]); gRX<1>(v, cw[21], sw[21]); gCZ<1,2>(v);
  gRY<2>(v, cw[22], sw[22]); gTOF<2,3,0>(v);
  gRY<3>(v, cx[3], sx[3]); gRZ<3>(v, cw[23], sw[23]); gCSWAP<3,0,1>(v);
}

DEVI float rlane(float v, int l) {
  return __int_as_float(__builtin_amdgcn_readlane(__float_as_int(v), l));
}

__global__ __launch_bounds__(256, 4)
void qsim(const float* __restrict__ x1, const float* __restrict__ x2,
          const float* __restrict__ q, float* __restrict__ out, int B)
{
  const int b = blockIdx.x * blockDim.x + threadIdx.x;
  if (b >= B) return;

  // batch-uniform w sincos: lanes 0..23 compute, broadcast via readlane
  const int lane = threadIdx.x & 63;
  float qv = 0.f;
  if (lane < 24) qv = q[lane];
  float mys, myc;
  __sincosf(0.5f * qv, &mys, &myc);

  float cw[24], sw[24];
#pragma unroll
  for (int k = 0; k < 24; ++k) { cw[k] = rlane(myc, k); sw[k] = rlane(mys, k); }

  const float4 xa = reinterpret_cast<const float4*>(x1)[b];
  const float4 xb = reinterpret_cast<const float4*>(x2)[b];
  float ca[4], sa[4], cb[4], sb[4];
  __sincosf(0.5f * xa.x, &sa[0], &ca[0]);
  __sincosf(0.5f * xa.y, &sa[1], &ca[1]);
  __sincosf(0.5f * xa.z, &sa[2], &ca[2]);
  __sincosf(0.5f * xa.w, &sa[3], &ca[3]);
  __sincosf(0.5f * xb.x, &sb[0], &cb[0]);
  __sincosf(0.5f * xb.y, &sb[1], &cb[1]);
  __sincosf(0.5f * xb.z, &sb[2], &cb[2]);
  __sincosf(0.5f * xb.w, &sb[3], &cb[3]);

  // both states start at H^4|0> = uniform 1/4
  f2 vA[16], vB[16];
#pragma unroll
  for (int i = 0; i < 16; ++i) {
    vA[i] = mk(0.25f, 0.f);
    vB[i] = mk(0.25f, 0.f);
  }

  fwd(vA, ca, sa, cw, sw);
  fwd(vB, cb, sb, cw, sw);

  // out = |<vB, vA>|^2 = |sum conj(vB_i) * vA_i|^2
  f2 acc = mk(0.f, 0.f);   // (re, im) packed accumulate
#pragma unroll
  for (int i = 0; i < 16; ++i) {
    // re += Bx*Ax + By*Ay ; im += Bx*Ay - By*Ax
    f2 t1 = mk(vA[i].x, vA[i].y) * sp(vB[i].x);      // (Bx*Ax, Bx*Ay)
    f2 t2 = mk(vA[i].y, -vA[i].x) * sp(vB[i].y);     // (By*Ay, -By*Ax)
    acc = acc + t1 + t2;
  }
  out[b] = acc.x * acc.x + acc.y * acc.y;
}

extern "C" void kernel_launch(void* const* d_in, const int* in_sizes, int n_in,
                              void* d_out, int out_size, void* d_ws, size_t ws_size,
                              hipStream_t stream) {
  const float* x1 = (const float*)d_in[0];
  const float* x2 = (const float*)d_in[1];
  const float* q  = (const float*)d_in[2];
  float* out = (float*)d_out;
  const int B = in_sizes[0] / 4;
  const int block = 256;
  const int grid = (B + block - 1) / block;
  qsim<<<grid, block, 0, stream>>>(x1, x2, q, out, B);
}